// Round 3
// baseline (68.333 us; speedup 1.0000x reference)
//
#include <hip/hip_runtime.h>

#define NBINS  20
#define STRIDE 21   // 21 words per row: gcd(21,32)=1 -> conflict-free LDS banks

// Per-thread u32 fields (E <= 128 elements/thread):
//   fracsum [0:15)  (<= 255*E)
//   cnt     [15:23) (<= E)
//   tgt     [23:31) (<= E)
// Block-level u64 fields:
//   fracsum [0:24) | cnt [24:44) | tgt [44:64)
// sum_p per bin = 0.05 * (cnt*bin + fracsum/256).

__global__ __launch_bounds__(256) void ace_hist(const float* __restrict__ preds,
                                                const int* __restrict__ tgt,
                                                float* __restrict__ ws, int n) {
    __shared__ __align__(16) unsigned int h32[256 * STRIDE];  // 21504 B
    unsigned long long* h64 = (unsigned long long*)h32;       // reused as [128][21]

    const int t = threadIdx.x;
    unsigned int* row = &h32[t * STRIDE];
    #pragma unroll
    for (int j = 0; j < STRIDE; ++j) row[j] = 0u;
    __syncthreads();

    // Race-free per-thread RMW: row is private, ds ops are in-order per wave.
#define PROC(pp, tt) do {                                         \
        unsigned _q = (unsigned)((pp) * 5120.0f);                 \
        unsigned _b = _q >> 8;                                    \
        _b = _b > 19u ? 19u : _b;                                 \
        unsigned _add = (_q & 255u) | (1u << 15)                  \
                      | ((unsigned)(tt) << 23);                   \
        row[_b] += _add;                                          \
    } while (0)

    const int n4 = n >> 2;
    const float4* p4 = (const float4*)preds;
    const int4*   t4 = (const int4*)tgt;
    const int stride = gridDim.x * blockDim.x;
    for (int i = blockIdx.x * blockDim.x + t; i < n4; i += stride) {
        float4 p  = p4[i];
        int4   tv = t4[i];
        PROC(p.x, tv.x);
        PROC(p.y, tv.y);
        PROC(p.z, tv.z);
        PROC(p.w, tv.w);
    }
    if (blockIdx.x == 0) {  // tail if n % 4 != 0 (empty for N=2^25)
        for (int i = (n4 << 2) + t; i < n; i += blockDim.x)
            PROC(preds[i], tgt[i]);
    }
#undef PROC
    __syncthreads();

    // Stage 0: thread t (<128) owns u32 rows {2t, 2t+1} and u64 row t —
    // the SAME bytes, so the region is thread-private: no barrier needed.
    // Read both rows fully into registers (static indexing), then write.
    if (t < 128) {
        const unsigned* r0 = &h32[(2 * t) * STRIDE];
        const unsigned* r1 = &h32[(2 * t + 1) * STRIDE];
        unsigned a[NBINS], c[NBINS];
        #pragma unroll
        for (int b = 0; b < NBINS; ++b) { a[b] = r0[b]; c[b] = r1[b]; }
        unsigned long long* d = &h64[t * STRIDE];
        #pragma unroll
        for (int b = 0; b < NBINS; ++b) {
            unsigned x = a[b], y = c[b];
            unsigned long long fr = (unsigned long long)((x & 0x7FFFu) + (y & 0x7FFFu));
            unsigned long long cn = (unsigned long long)(((x >> 15) & 0xFFu) + ((y >> 15) & 0xFFu));
            unsigned long long tg = (unsigned long long)((x >> 23) + (y >> 23));
            d[b] = fr | (cn << 24) | (tg << 44);
        }
    }
    __syncthreads();

    // In-place u64 tree over 128 rows.
    for (int off = 64; off >= 1; off >>= 1) {
        if (t < off) {
            unsigned long long* d = &h64[t * STRIDE];
            const unsigned long long* s = &h64[(t + off) * STRIDE];
            #pragma unroll
            for (int b = 0; b < NBINS; ++b) d[b] += s[b];
        }
        __syncthreads();
    }

    if (t < NBINS) {
        unsigned long long v = h64[t];
        float fr = (float)(unsigned)(v & 0xFFFFFFu);
        float cn = (float)(unsigned)((v >> 24) & 0xFFFFFu);
        float tg = (float)(unsigned)(v >> 44);
        size_t base = (size_t)blockIdx.x * 64;
        ws[base + t]             = cn;
        ws[base + NBINS + t]     = 0.05f * (cn * (float)t + fr * (1.0f / 256.0f));
        ws[base + 2 * NBINS + t] = tg;
    }
}

// Kernel 2: one block, 1024 threads (16 row-groups x 64 cols), 8-way unrolled
// independent accumulators, then the 20-bin epilogue.
__global__ __launch_bounds__(1024) void ace_reduce(const float* __restrict__ ws,
                                                   float* __restrict__ out, int nblk) {
    __shared__ float part[16][64];
    const int t = threadIdx.x;
    const int col = t & 63;
    const int g = t >> 6;  // 0..15
    float s = 0.0f;
    if (col < 3 * NBINS) {
        float a0 = 0, a1 = 0, a2 = 0, a3 = 0, a4 = 0, a5 = 0, a6 = 0, a7 = 0;
        int r = g;
        for (; r + 112 < nblk; r += 128) {
            a0 += ws[(size_t)(r      ) * 64 + col];
            a1 += ws[(size_t)(r +  16) * 64 + col];
            a2 += ws[(size_t)(r +  32) * 64 + col];
            a3 += ws[(size_t)(r +  48) * 64 + col];
            a4 += ws[(size_t)(r +  64) * 64 + col];
            a5 += ws[(size_t)(r +  80) * 64 + col];
            a6 += ws[(size_t)(r +  96) * 64 + col];
            a7 += ws[(size_t)(r + 112) * 64 + col];
        }
        for (; r < nblk; r += 16)
            a0 += ws[(size_t)r * 64 + col];
        s = ((a0 + a1) + (a2 + a3)) + ((a4 + a5) + (a6 + a7));
    }
    part[g][col] = s;
    __syncthreads();
    if (t < 64) {
        float fin = 0.0f;
        #pragma unroll
        for (int i = 0; i < 16; ++i) fin += part[i][t];
        part[0][t] = fin;
    }
    __syncthreads();
    if (t < 64) {
        float term = 0.0f;
        if (t < NBINS) {
            float cnt = part[0][t];
            float sp  = part[0][NBINS + t];
            float st  = part[0][2 * NBINS + t];
            if (cnt > 0.0f) term = fabsf(sp - st) / cnt;  // |e-o| = |sp-st|/cnt
        }
        for (int off = 32; off; off >>= 1)
            term += __shfl_down(term, off);
        if (t == 0) out[0] = term / (float)NBINS;
    }
}

extern "C" void kernel_launch(void* const* d_in, const int* in_sizes, int n_in,
                              void* d_out, int out_size, void* d_ws, size_t ws_size,
                              hipStream_t stream) {
    const float* preds = (const float*)d_in[0];
    const int*   tgt   = (const int*)d_in[1];
    float* out = (float*)d_out;
    float* ws  = (float*)d_ws;
    const int n = in_sizes[0];

    // 2048 blocks -> 64 elements/thread (fits u32 packing, E<=128 required).
    int nblk = 2048;
    if ((size_t)nblk * 64 * sizeof(float) > ws_size) nblk = 1024;

    ace_hist<<<nblk, 256, 0, stream>>>(preds, tgt, ws, n);
    ace_reduce<<<1, 1024, 0, stream>>>(ws, out, nblk);
}